// Round 6
// baseline (45.695 us; speedup 1.0000x reference)
//
#include <hip/hip_runtime.h>

#define NN 128   // modes

// Folded per-layer MMI coefficients: a = A*e^{i th}, b = iB*e^{i th}
// (phase diag folded into the MMI matrix column that multiplies the even row)
struct Coef { float2 a0, b0, a1, b1; };

__device__ __forceinline__ Coef make_coef(float2 th) {
    const float A = sqrtf(0.95f * 0.505f);
    const float B = sqrtf(0.95f * 0.495f);
    float s0, c0, s1, c1;
    __sincosf(th.x, &s0, &c0);
    __sincosf(th.y, &s1, &c1);
    Coef cf;
    cf.a0 = make_float2(A * c0, A * s0);
    cf.b0 = make_float2(-B * s0, B * c0);
    cf.a1 = make_float2(A * c1, A * s1);
    cf.b1 = make_float2(-B * s1, B * c1);
    return cf;
}

// One wave per output column c. Lane l holds rows 4l..4l+3 (complex) in regs.
// 254 folded mixing layers, software-pipelined: theta prefetched 4 ahead,
// sincos+coef computed 1 layer ahead (off the state-dependency chain).
// Output: Re(T[n][c]) as f32, row-major (n,c).
__global__ __launch_bounds__(64) void mesh_kernel(
    const float* __restrict__ theta_in,    // (128,)
    const float* __restrict__ theta_even,  // (255,128)
    const float* __restrict__ theta_out,   // (128,)
    float* __restrict__ out)               // (128,128) f32 = Re(arch)
{
    const int c = blockIdx.x;
    const int l = threadIdx.x;

    const float A  = sqrtf(0.95f * 0.505f);
    const float B  = sqrtf(0.95f * 0.495f);
    const float C2 = sqrtf(0.98f * 0.01f);
    const float S2 = sqrtf(0.98f * 0.99f);

    // prologue loads (all issued before any dependent use)
    const float2* tev = (const float2*)(theta_even) + l;  // float2 idx: j*64 + l
    float2 th0 = tev[0];
    float2 tn1 = tev[64];
    float2 tn2 = tev[2 * 64];
    float2 tn3 = tev[3 * 64];
    float2 tho = ((const float2*)theta_out)[l];   // theta_out[2l], [2l+1]
    float  thi = theta_in[c];

    // init: column c after MMI_IN -> rows 2c: A*e^{i thi}, 2c+1: iB*e^{i thi}
    float2 v0 = make_float2(0.f, 0.f), v1 = v0, v2 = v0, v3 = v0;
    {
        float s, co;
        __sincosf(thi, &s, &co);
        float2 r0 = make_float2(A * co, A * s);
        float2 r1 = make_float2(-B * s, B * co);
        if (l == (c >> 1)) {
            if (c & 1) { v2 = r0; v3 = r1; }
            else       { v0 = r0; v1 = r1; }
        }
    }

    Coef cf = make_coef(th0);   // layer 0 coefficients

    #pragma unroll 2
    for (int j = 0; j < 254; ++j) {
        // prefetch theta[j+4] (clamped; uniform index -> scalar min)
        int jl = j + 4; if (jl > 254) jl = 254;
        float2 th_load = tev[jl * 64];

        // next layer's coefficients — independent of state, hides sincos latency
        Coef cfn = make_coef(tn1);

        // folded layer j: n0 = a0*v0 + iB*v1 ; n1 = b0*v0 + A*v1 (3-FMA dots)
        float2 n0, n1, n2, n3;
        n0.x = cf.a0.x * v0.x - cf.a0.y * v0.y - B * v1.y;
        n0.y = cf.a0.x * v0.y + cf.a0.y * v0.x + B * v1.x;
        n1.x = cf.b0.x * v0.x - cf.b0.y * v0.y + A * v1.x;
        n1.y = cf.b0.x * v0.y + cf.b0.y * v0.x + A * v1.y;
        n2.x = cf.a1.x * v2.x - cf.a1.y * v2.y - B * v3.y;
        n2.y = cf.a1.x * v2.y + cf.a1.y * v2.x + B * v3.x;
        n3.x = cf.b1.x * v2.x - cf.b1.y * v2.y + A * v3.x;
        n3.y = cf.b1.x * v2.y + cf.b1.y * v2.x + A * v3.y;

        if (!(j & 1)) {
            // CROSS: (n1,n2) lane-local; (n3_l, n0_{l+1}) cross-lane; corners *= S2
            float2 m1, m2, m0, m3;
            m1.x = C2 * n1.x - S2 * n2.y;  m1.y = C2 * n1.y + S2 * n2.x;
            m2.x = C2 * n2.x - S2 * n1.y;  m2.y = C2 * n2.y + S2 * n1.x;
            float nxt_re = __shfl_down(n0.x, 1);
            float nxt_im = __shfl_down(n0.y, 1);
            float prv_re = __shfl_up(n3.x, 1);
            float prv_im = __shfl_up(n3.y, 1);
            m3 = (l == 63)
                ? make_float2(S2 * n3.x, S2 * n3.y)
                : make_float2(C2 * n3.x - S2 * nxt_im, C2 * n3.y + S2 * nxt_re);
            m0 = (l == 0)
                ? make_float2(S2 * n0.x, S2 * n0.y)
                : make_float2(C2 * n0.x - S2 * prv_im, C2 * n0.y + S2 * prv_re);
            v0 = m0; v1 = m1; v2 = m2; v3 = m3;
        } else {
            v0 = n0; v1 = n1; v2 = n2; v3 = n3;
        }

        // rotate pipeline
        tn1 = tn2; tn2 = tn3; tn3 = th_load;
        cf = cfn;
    }

    // Exit: cf = make_coef(theta[254]). Final diag(theta[254]) + MMI_OUT row
    // is exactly the folded form: out_2l = a0*v0 + iB*v1, out_2l+1 = a1*v2 + iB*v3.
    float2 o0, o1;
    o0.x = cf.a0.x * v0.x - cf.a0.y * v0.y - B * v1.y;
    o0.y = cf.a0.x * v0.y + cf.a0.y * v0.x + B * v1.x;
    o1.x = cf.a1.x * v2.x - cf.a1.y * v2.y - B * v3.y;
    o1.y = cf.a1.x * v2.y + cf.a1.y * v2.x + B * v3.x;

    // diag(d_out) rotation, keep real part only
    float so0, co0, so1, co1;
    __sincosf(tho.x, &so0, &co0);
    __sincosf(tho.y, &so1, &co1);
    out[(2 * l)     * NN + c] = co0 * o0.x - so0 * o0.y;
    out[(2 * l + 1) * NN + c] = co1 * o1.x - so1 * o1.y;
}

extern "C" void kernel_launch(void* const* d_in, const int* in_sizes, int n_in,
                              void* d_out, int out_size, void* d_ws, size_t ws_size,
                              hipStream_t stream) {
    // Identify inputs by SIZE: theta_even is the unique large (32640) array;
    // the two 128-elem arrays keep relative order (theta_in before theta_out).
    int ev = 0;
    for (int i = 0; i < n_in; ++i) if (in_sizes[i] > 1000) ev = i;
    int a = -1, b = -1;
    for (int i = 0; i < n_in; ++i) {
        if (i == ev) continue;
        if (a < 0) a = i; else if (b < 0) b = i;
    }
    const float* th_in  = (const float*)d_in[a];
    const float* th_ev  = (const float*)d_in[ev];
    const float* th_out = (const float*)d_in[b];
    mesh_kernel<<<dim3(NN), dim3(64), 0, stream>>>(th_in, th_ev, th_out, (float*)d_out);
}